// Round 7
// baseline (198.388 us; speedup 1.0000x reference)
//
#include <hip/hip_runtime.h>
#include <hip/hip_bf16.h>

#define BATCH  4096
#define UNITS  1024
#define CDIM   2048   // K = UNITS + IN_DIM
#define NDIM   4096   // 4 * UNITS (f, i, c, o)

typedef __attribute__((ext_vector_type(8))) short bf16x8;
typedef __attribute__((ext_vector_type(4))) short bf16x4;
typedef __attribute__((ext_vector_type(4))) float f32x4;

__device__ __forceinline__ void gload_lds16(const void* g, void* l) {
    __builtin_amdgcn_global_load_lds(
        (const __attribute__((address_space(1))) unsigned int*)g,
        (__attribute__((address_space(3))) unsigned int*)l, 16, 0, 0);
}

__device__ __forceinline__ float sigm(float x) { return 1.f / (1.f + __expf(-x)); }
__device__ __forceinline__ float tanh_fast(float x) { return 2.f / (1.f + __expf(-2.f * x)) - 1.f; }

__device__ __forceinline__ short f2bf(float f) {
    __hip_bfloat16 h = __float2bfloat16(f);
    return *reinterpret_cast<short*>(&h);
}

// ---- prep v3 (FROZEN control: ~30 us, near 128 MB roofline) -----------------
// Wt row layout (gate-interleaved, 128-periodic):
//   n(u,g) = (u>>5)*128 + ((u>>4)&1)*64 + g*16 + (u&15)
__global__ __launch_bounds__(256) void prep(
        const float* __restrict__ h, const float* __restrict__ in,
        const float* __restrict__ Wf, const float* __restrict__ Wi,
        const float* __restrict__ Wc, const float* __restrict__ Wo,
        __hip_bfloat16* __restrict__ x, __hip_bfloat16* __restrict__ Wt) {
    __shared__ float lds[64 * 65];
    int b = blockIdx.x, tid = threadIdx.x;
    if (b < 4096) {
        int t   = b * 256 + tid;
        int row = t >> 8;
        int c8  = (t & 255) << 3;
        const float* src = (c8 < UNITS) ? (h + (size_t)row * UNITS + c8)
                                        : (in + (size_t)row * UNITS + (c8 - UNITS));
        float4 v0 = ((const float4*)src)[0];
        float4 v1 = ((const float4*)src)[1];
        bf16x8 o;
        o[0] = f2bf(v0.x); o[1] = f2bf(v0.y); o[2] = f2bf(v0.z); o[3] = f2bf(v0.w);
        o[4] = f2bf(v1.x); o[5] = f2bf(v1.y); o[6] = f2bf(v1.z); o[7] = f2bf(v1.w);
        *(bf16x8*)(x + (size_t)row * CDIM + c8) = o;
    } else {
        int idx = b - 4096;               // 2048 blocks = g(4) x kt(32) x ut(16)
        int g = idx >> 9, kt = (idx >> 4) & 31, ut = idx & 15;
        const float* W = (g == 0) ? Wf : (g == 1) ? Wi : (g == 2) ? Wc : Wo;
        int k0 = kt * 64, u0 = ut * 64;
        int r16 = tid & 15, hi = tid >> 4;
#pragma unroll
        for (int it = 0; it < 4; ++it) {
            int kl = it * 16 + hi;
            float4 v = *(const float4*)&W[(size_t)(k0 + kl) * UNITS + u0 + r16 * 4];
            float* d = &lds[kl * 65 + r16 * 4];
            d[0] = v.x; d[1] = v.y; d[2] = v.z; d[3] = v.w;
        }
        __syncthreads();
#pragma unroll
        for (int it = 0; it < 4; ++it) {
            int ul = it * 16 + hi;
            int u  = u0 + ul;
            int n  = ((u >> 5) << 7) + (((u >> 4) & 1) << 6) + (g << 4) + (u & 15);
            bf16x4 o;
#pragma unroll
            for (int j = 0; j < 4; ++j) o[j] = f2bf(lds[(r16 * 4 + j) * 65 + ul]);
            *(bf16x4*)(Wt + (size_t)n * CDIM + k0 + r16 * 4) = o;
        }
    }
}

// ---- gemm v5: 8-phase, ALL LDS reads in inline asm --------------------------
// Same schedule/slots/vmcnt as R6 (derivation in R6 comments; proven race-free
// by construction). Single change: K-loop LDS reads are inline-asm
// ds_read_b128 on raw 32-bit LDS addresses (compile-time offset: immediates),
// with explicit s_waitcnt lgkmcnt(0) + sched_barrier(0) before MFMAs (rule
// #18). Theory: R6's pointer-based ds_reads from the dynamic smem blob could
// not be alias-disambiguated from in-flight global_load_lds writes -> backend
// inserted a vmcnt drain before the reads every phase (the flat ~1400
// cyc/phase stall). Removing compiler-visible LDS reads removes the drain.
// LDS map (bytes): A[p][h] @ (p*2+h)*16384 ; B[p][h] @ 65536+(p*2+h)*16384.
__global__ __launch_bounds__(512, 2) void gemm_lstm(
    const __hip_bfloat16* __restrict__ A,    // [BATCH, CDIM] bf16
    const __hip_bfloat16* __restrict__ Bt,   // [NDIM, CDIM] bf16, gate-interleaved
    const float* __restrict__ b_f, const float* __restrict__ b_i,
    const float* __restrict__ b_c, const float* __restrict__ b_o,
    const float* __restrict__ cell,          // [BATCH, UNITS]
    float* __restrict__ out)                 // [2, BATCH, UNITS]: hidden, cell
{
    extern __shared__ short smem[];          // 65536 shorts = 128 KB
    const int K = CDIM;

    int bid = blockIdx.x;
    int nb  = (bid & 7) * 2 + ((bid >> 3) & 1);   // 0..15 (XCD swizzle)
    int mb  = bid >> 4;                           // 0..15
    int m0  = mb * 256, n0 = nb * 256;

    int tid  = threadIdx.x;
    int w    = tid >> 6, lane = tid & 63;
    int wm   = w >> 2, wn2 = w & 3;
    int quad = lane >> 4, r16 = lane & 15;

    f32x4 acc[8][4];
#pragma unroll
    for (int i = 0; i < 8; ++i)
#pragma unroll
        for (int j = 0; j < 4; ++j) acc[i][j] = (f32x4){0.f, 0.f, 0.f, 0.f};

    const short* Ag0 = (const short*)A  + (size_t)(m0)       * K;
    const short* Ag1 = (const short*)A  + (size_t)(m0 + 128) * K;
    const short* Bg0 = (const short*)Bt + (size_t)(n0)       * K;
    const short* Bg1 = (const short*)Bt + (size_t)(n0 + 128) * K;

    short* lds = smem;
    // 32-bit LDS base + per-wave read addresses (bytes)
    unsigned SB  = (unsigned)(size_t)(__attribute__((address_space(3))) short*)smem;
    unsigned kc0 = (unsigned)((quad ^ (r16 & 7)) * 16);
    unsigned kc1 = (unsigned)(((quad + 4) ^ (r16 & 7)) * 16);
    unsigned aA  = SB + wm * 16384 + r16 * 128;           // + p*32768 + kc
    unsigned aB  = SB + 65536 + wn2 * 8192 + r16 * 128;   // + p*32768 + kc

    bf16x8 bfr[4];

#define STG(SRC, DSTOFF, KT)                                                   \
    { _Pragma("unroll")                                                        \
      for (int q_ = 0; q_ < 2; ++q_) {                                         \
          int s_ = q_ * 512 + tid;                                             \
          int row_ = s_ >> 3, cg_ = (s_ & 7) ^ (row_ & 7);                     \
          gload_lds16(SRC + (size_t)row_ * K + (KT) * 64 + cg_ * 8,            \
                      lds + (DSTOFF) + s_ * 8);                                \
      } }

#define DSR(DST, ADDR, OFFTXT)                                                 \
    asm volatile("ds_read_b128 %0, %1 " OFFTXT : "=v"(DST) : "v"(ADDR) : "memory");

#define PHASE(P, KS, IH, STAGE_CODE, WAIT_CODE)                                \
    {                                                                          \
        unsigned adA_ = aA + (P) * 32768 + ((KS) ? kc1 : kc0);                 \
        bf16x8 af0, af1, af2, af3;                                             \
        if ((IH) == 0) {                                                       \
            unsigned adB_ = aB + (P) * 32768 + ((KS) ? kc1 : kc0);             \
            DSR(af0, adA_, "")                                                 \
            DSR(af1, adA_, "offset:2048")                                      \
            DSR(af2, adA_, "offset:4096")                                      \
            DSR(af3, adA_, "offset:6144")                                      \
            DSR(bfr[0], adB_, "")                                              \
            DSR(bfr[1], adB_, "offset:2048")                                   \
            DSR(bfr[2], adB_, "offset:4096")                                   \
            DSR(bfr[3], adB_, "offset:6144")                                   \
        } else {                                                               \
            DSR(af0, adA_, "offset:8192")                                      \
            DSR(af1, adA_, "offset:10240")                                     \
            DSR(af2, adA_, "offset:12288")                                     \
            DSR(af3, adA_, "offset:14336")                                     \
        }                                                                      \
        STAGE_CODE;                                                            \
        asm volatile("s_barrier" ::: "memory");                                \
        asm volatile("s_waitcnt lgkmcnt(0)" ::: "memory");                     \
        __builtin_amdgcn_sched_barrier(0);                                     \
        __builtin_amdgcn_s_setprio(1);                                         \
        _Pragma("unroll")                                                      \
        for (int j_ = 0; j_ < 4; ++j_) {                                       \
            acc[(IH)*4+0][j_] = __builtin_amdgcn_mfma_f32_16x16x32_bf16(af0, bfr[j_], acc[(IH)*4+0][j_], 0, 0, 0); \
            acc[(IH)*4+1][j_] = __builtin_amdgcn_mfma_f32_16x16x32_bf16(af1, bfr[j_], acc[(IH)*4+1][j_], 0, 0, 0); \
            acc[(IH)*4+2][j_] = __builtin_amdgcn_mfma_f32_16x16x32_bf16(af2, bfr[j_], acc[(IH)*4+2][j_], 0, 0, 0); \
            acc[(IH)*4+3][j_] = __builtin_amdgcn_mfma_f32_16x16x32_bf16(af3, bfr[j_], acc[(IH)*4+3][j_], 0, 0, 0); \
        }                                                                      \
        __builtin_amdgcn_s_setprio(0);                                         \
        __builtin_amdgcn_sched_barrier(0);                                     \
        WAIT_CODE;                                                             \
        asm volatile("s_barrier" ::: "memory");                                \
    }

#define VM2 asm volatile("s_waitcnt vmcnt(2)" ::: "memory")
#define VM0 asm volatile("s_waitcnt vmcnt(0)" ::: "memory")
#define NOPX ((void)0)

    // Prologue: stage tile0 -> p0 (4 halves) + B[p1,h0](tile1); retire p0.
    STG(Ag0, 0,     0)
    STG(Ag1, 8192,  0)
    STG(Bg0, 32768, 0)
    STG(Bg1, 40960, 0)
    STG(Bg0, 49152, 1)
    VM2;
    asm volatile("s_barrier" ::: "memory");

    for (int u = 0; u < 15; ++u) {
        int t1 = 2 * u + 1, t2 = 2 * u + 2, t3 = 2 * u + 3;
        PHASE(0, 0, 0, STG(Ag0, 16384, t1), NOPX)   // P1: stage A[p1,h0](t1)
        PHASE(0, 0, 1, STG(Ag1, 24576, t1), NOPX)   // P2: stage A[p1,h1](t1)
        PHASE(0, 1, 0, STG(Bg1, 57344, t1), NOPX)   // P3: stage B[p1,h1](t1)
        PHASE(0, 1, 1, STG(Bg0, 32768, t2), VM2)    // P4: stage B[p0,h0](t2); retire p1
        PHASE(1, 0, 0, STG(Bg1, 40960, t2), NOPX)   // P5: stage B[p0,h1](t2)
        PHASE(1, 0, 1, STG(Ag0, 0,     t2), NOPX)   // P6: stage A[p0,h0](t2)
        PHASE(1, 1, 0, STG(Ag1, 8192,  t2), NOPX)   // P7: stage A[p0,h1](t2)
        PHASE(1, 1, 1, STG(Bg0, 49152, t3), VM2)    // P8: stage B[p1,h0](t3); retire p0
    }
    // Tail u=15: tiles 30 (p0) / 31 (p1); only tile-31 stages remain.
    PHASE(0, 0, 0, STG(Ag0, 16384, 31), NOPX)
    PHASE(0, 0, 1, STG(Ag1, 24576, 31), NOPX)
    PHASE(0, 1, 0, STG(Bg1, 57344, 31), NOPX)
    PHASE(0, 1, 1, NOPX, VM0)
    PHASE(1, 0, 0, NOPX, NOPX)
    PHASE(1, 0, 1, NOPX, NOPX)
    PHASE(1, 1, 0, NOPX, NOPX)
    PHASE(1, 1, 1, NOPX, NOPX)

#undef PHASE
#undef DSR
#undef STG
#undef VM2
#undef VM0
#undef NOPX

    // ---- fused LSTM epilogue (R0-proven mapping; j = gate) ------------------
    int uo = nb * 64 + (wn2 >> 1) * 32 + (wn2 & 1) * 16 + r16;
    float bfv = b_f[uo], biv = b_i[uo], bcv = b_c[uo], bov = b_o[uo];
    float* out_h = out;
    float* out_c = out + (size_t)BATCH * UNITS;
#pragma unroll
    for (int i = 0; i < 8; ++i) {
#pragma unroll
        for (int rr = 0; rr < 4; ++rr) {
            int m = m0 + wm * 128 + i * 16 + quad * 4 + rr;
            float fg = sigm(acc[i][0][rr] + bfv);
            float ig = sigm(acc[i][1][rr] + biv);
            float cc = tanh_fast(acc[i][2][rr] + bcv);
            float og = sigm(acc[i][3][rr] + bov);
            float cold = cell[(size_t)m * UNITS + uo];
            float cn = fg * cold + ig * cc;
            out_h[(size_t)m * UNITS + uo] = og * tanh_fast(cn);
            out_c[(size_t)m * UNITS + uo] = cn;
        }
    }
}

extern "C" void kernel_launch(void* const* d_in, const int* in_sizes, int n_in,
                              void* d_out, int out_size, void* d_ws, size_t ws_size,
                              hipStream_t stream) {
    const float* inputs = (const float*)d_in[0];
    const float* hidden = (const float*)d_in[1];
    const float* cell   = (const float*)d_in[2];
    const float* Wf = (const float*)d_in[3];
    const float* bf_ = (const float*)d_in[4];
    const float* Wi = (const float*)d_in[5];
    const float* bi_ = (const float*)d_in[6];
    const float* Wc = (const float*)d_in[7];
    const float* bc_ = (const float*)d_in[8];
    const float* Wo = (const float*)d_in[9];
    const float* bo_ = (const float*)d_in[10];
    float* out = (float*)d_out;

    char* ws = (char*)d_ws;
    __hip_bfloat16* x  = (__hip_bfloat16*)ws;                  // 16 MB
    __hip_bfloat16* Wt = (__hip_bfloat16*)(ws + (16u << 20));  // 16 MB

    static bool attr_set = false;
    if (!attr_set) {
        hipFuncSetAttribute(reinterpret_cast<const void*>(gemm_lstm),
                            hipFuncAttributeMaxDynamicSharedMemorySize, 131072);
        attr_set = true;
    }

    prep<<<dim3(6144), dim3(256), 0, stream>>>(hidden, inputs, Wf, Wi, Wc, Wo, x, Wt);
    gemm_lstm<<<dim3(256), dim3(512), 131072, stream>>>(
        x, Wt, bf_, bi_, bc_, bo_, cell, out);
}